// Round 14
// baseline (461.428 us; speedup 1.0000x reference)
//
#include <hip/hip_runtime.h>
#include <math.h>

#define H 128
#define N_NODES 10000
#define N_EDGES 160000

typedef float f32x4 __attribute__((ext_vector_type(4)));
typedef short s16x8 __attribute__((ext_vector_type(8)));

#define WAVE_LDS_FENCE() do { \
  asm volatile("s_waitcnt lgkmcnt(0)" ::: "memory"); \
  __builtin_amdgcn_sched_barrier(0); \
} while (0)

__device__ __forceinline__ float sigf(float x){ return 1.0f/(1.0f + __expf(-x)); }
__device__ __forceinline__ float eluf(float x){ return x > 0.0f ? x : (__expf(x) - 1.0f); }

__device__ __forceinline__ unsigned short f2bf(float f){
  unsigned int u = __float_as_uint(f);
  unsigned int r = (u + 0x7fffu + ((u >> 16) & 1u)) >> 16;
  return (unsigned short)r;
}
__device__ __forceinline__ float bf2f(unsigned short s){
  return __uint_as_float(((unsigned int)s) << 16);
}

__device__ __forceinline__ f32x4 MFMA16(s16x8 a, s16x8 b, f32x4 c){
  return __builtin_amdgcn_mfma_f32_16x16x32_bf16(a, b, c, 0, 0, 0);
}

__device__ __forceinline__ s16x8 loadA_f32(const float* p){
  float4 a = *(const float4*)p;
  float4 b = *(const float4*)(p+4);
  s16x8 r;
  r[0]=(short)f2bf(a.x); r[1]=(short)f2bf(a.y); r[2]=(short)f2bf(a.z); r[3]=(short)f2bf(a.w);
  r[4]=(short)f2bf(b.x); r[5]=(short)f2bf(b.y); r[6]=(short)f2bf(b.z); r[7]=(short)f2bf(b.w);
  return r;
}

// ---------------- edge sort by (masked, src): hist(active) -> scan -> scatter ----------------
__global__ __launch_bounds__(256) void hist_kernel(
    const int* __restrict__ src, const float* __restrict__ ed, int* __restrict__ count)
{
  int e = blockIdx.x*256 + threadIdx.x;
  if (e < N_EDGES && ed[e] < 8.0f) atomicAdd(&count[src[e]], 1);
}

__global__ __launch_bounds__(256) void scan_kernel(
    const int* __restrict__ count, int* __restrict__ offsets)
{
  __shared__ int tmp[256];
  __shared__ int sbase;
  if (threadIdx.x == 0) sbase = 0;
  __syncthreads();
  for (int c0 = 0; c0 < N_NODES; c0 += 256) {
    int i = c0 + threadIdx.x;
    int v = (i < N_NODES) ? count[i] : 0;
    tmp[threadIdx.x] = v;
    __syncthreads();
    for (int off = 1; off < 256; off <<= 1) {
      int t = (threadIdx.x >= off) ? tmp[threadIdx.x - off] : 0;
      __syncthreads();
      tmp[threadIdx.x] += t;
      __syncthreads();
    }
    if (i < N_NODES) offsets[i] = sbase + tmp[threadIdx.x] - v;
    __syncthreads();
    if (threadIdx.x == 255) sbase += tmp[255];
    __syncthreads();
  }
  if (threadIdx.x == 0) offsets[N_NODES] = sbase;   // n_active
}

__global__ __launch_bounds__(256) void scatter_kernel(
    const int* __restrict__ src, const int* __restrict__ tgt, const float* __restrict__ ed,
    const int* __restrict__ offsets,
    int* __restrict__ cursor, int* __restrict__ mcur, int* __restrict__ perm,
    int* __restrict__ srcp, int* __restrict__ tgtp, float* __restrict__ edp)
{
  int e = blockIdx.x*256 + threadIdx.x;
  if (e < N_EDGES) {
    int s = src[e];
    float r = ed[e];
    int pos;
    if (r < 8.0f) pos = atomicAdd(&cursor[s], 1);
    else          pos = offsets[N_NODES] + atomicAdd(mcur, 1);
    perm[pos] = e;
    srcp[pos] = s;
    tgtp[pos] = tgt[e];
    edp[pos]  = r;
  }
}

// ---------------- prep_edges: permuted bf16 copies of cs, pw (zeros past n_active) ----------------
__global__ __launch_bounds__(256) void prep_edges(
    const float* __restrict__ cs, const float* __restrict__ pw, const int* __restrict__ perm,
    const int* __restrict__ nact,
    unsigned short* __restrict__ csb, unsigned short* __restrict__ pwb)
{
  int idx = blockIdx.x*256 + threadIdx.x;   // over N_EDGES*8
  if (idx >= N_EDGES*8) return;
  int pos = idx >> 3, kc = idx & 7;
  if (pos < *nact) {
    int e = perm[pos];
    s16x8 c = loadA_f32(&cs[(size_t)e*64 + kc*8]);
    s16x8 p = loadA_f32(&pw[(size_t)e*64 + kc*8]);
    *(s16x8*)&csb[(size_t)pos*64 + kc*8] = c;
    *(s16x8*)&pwb[(size_t)pos*64 + kc*8] = p;
  } else {
    s16x8 z = {0,0,0,0,0,0,0,0};
    *(s16x8*)&csb[(size_t)pos*64 + kc*8] = z;
    *(s16x8*)&pwb[(size_t)pos*64 + kc*8] = z;
  }
}

// ---------------- prep_weights: W1,W2,W2g,embW -> bf16 [col][k] ----------------
__global__ __launch_bounds__(256) void prep_weights(
    const float* __restrict__ W1, const float* __restrict__ W2, const float* __restrict__ W2g,
    const float* __restrict__ embW,
    unsigned short* __restrict__ w1t, unsigned short* __restrict__ w2t,
    unsigned short* __restrict__ w2gt, unsigned short* __restrict__ embt)
{
  int idx = blockIdx.x*256 + threadIdx.x;
  if (idx < 3*8192) {
    int l = idx / 8192, r = idx % 8192;
    int c = r >> 6, k = r & 63;
    w1t[idx] = f2bf(W1[l*8192 + k*128 + c]);
    w2t[idx] = f2bf(W2[l*8192 + k*128 + c]);
  } else if (idx < 3*8192 + 3*4096) {
    int idx2 = idx - 3*8192;
    int l = idx2 / 4096, r = idx2 % 4096;
    int c = r >> 6, k = r & 63;
    w2gt[idx2] = f2bf(W2g[l*4096 + k*64 + c]);
  } else {
    int idx3 = idx - (3*8192 + 3*4096);
    if (idx3 < 16384) {
      int c = idx3 >> 7, k = idx3 & 127;
      embt[idx3] = f2bf(embW[k*128 + c]);
    }
  }
}

// ---------------- prep_nodew: bf16 [col][k] transposes for node GEMMs ----------------
__global__ __launch_bounds__(256) void prep_nodew(
    const float* __restrict__ Wg, const float* __restrict__ Wm,
    const float* __restrict__ p1, const float* __restrict__ p2, const float* __restrict__ psiW,
    unsigned short* __restrict__ wnt, unsigned short* __restrict__ wpt)
{
  int idx = blockIdx.x*256 + threadIdx.x;
  if (idx < 3*98304) {
    int l = idx / 98304, r = idx % 98304;
    int j = r >> 7, k = r & 127;
    float v;
    if (j < 384) v = Wg[l*49152 + (j>>7)*16384 + k*128 + (j&127)];
    else { int jj = j - 384; v = Wm[l*49152 + (jj>>7)*16384 + k*128 + (jj&127)]; }
    wnt[idx] = f2bf(v);
  } else {
    int idx2 = idx - 3*98304;
    if (idx2 < 3*49152) {
      int l = idx2 / 49152, r = idx2 % 49152;
      int j = r >> 7, k = r & 127;
      float v;
      if (j < 128)      v = p1 [l*16384 + k*128 + j];
      else if (j < 256) v = p2 [l*16384 + k*128 + (j-128)];
      else              v = psiW[l*16384 + k*128 + (j-256)];
      wpt[idx2] = f2bf(v);
    }
  }
}

// ---------------- embed_pack: h = sig(x@embW) + layer-0 pack GEMM, 16 nodes/block ----------------
__global__ __launch_bounds__(256) void embed_pack(
    const float* __restrict__ x, const unsigned short* __restrict__ embt,
    const unsigned short* __restrict__ wnt,
    float* __restrict__ h_out,
    unsigned short* __restrict__ spackb, unsigned short* __restrict__ tpackb)
{
  __shared__ unsigned short hb[16*128];          // 4 KB swizzled bf16 h
  int tid = threadIdx.x, wave = tid >> 6, lane = tid & 63;
  int row = lane & 15, kg = lane >> 4;
  int nbase = blockIdx.x*16;
  const float* xr = &x[(size_t)(nbase + row)*H];
  s16x8 a[4];
  #pragma unroll
  for (int ks = 0; ks < 4; ks++) a[ks] = loadA_f32(xr + ks*32 + kg*8);

  f32x4 acc[2];
  #pragma unroll
  for (int ti = 0; ti < 2; ti++) { acc[ti][0]=0.f; acc[ti][1]=0.f; acc[ti][2]=0.f; acc[ti][3]=0.f; }
  #pragma unroll
  for (int ti = 0; ti < 2; ti++) {
    int col = (wave*2 + ti)*16 + row;
    #pragma unroll
    for (int ks = 0; ks < 4; ks++) {
      s16x8 b = *(const s16x8*)&embt[(size_t)col*128 + ks*32 + kg*8];
      acc[ti] = MFMA16(a[ks], b, acc[ti]);
    }
  }
  #pragma unroll
  for (int ti = 0; ti < 2; ti++) {
    int col = (wave*2 + ti)*16 + row;
    #pragma unroll
    for (int r = 0; r < 4; r++) {
      int ln = kg*4 + r;
      float v = sigf(acc[ti][r]);
      h_out[(size_t)(nbase + ln)*H + col] = v;
      int byt = (ln << 8) + (col << 1);
      byt ^= (ln & 7) << 4;
      *(unsigned short*)((char*)hb + byt) = f2bf(v);
    }
  }
  __syncthreads();

  // pack GEMM from LDS
  s16x8 an[4];
  #pragma unroll
  for (int ks = 0; ks < 4; ks++) {
    int byt = (row << 8) + ks*64 + kg*16;
    byt ^= (row & 7) << 4;
    an[ks] = *(s16x8*)((char*)hb + byt);
  }
  #pragma unroll
  for (int ti = 0; ti < 2; ti++) {
    int t = wave*2 + ti;
    f32x4 pacc[6];
    #pragma unroll
    for (int ch = 0; ch < 6; ch++) { pacc[ch][0]=0.f; pacc[ch][1]=0.f; pacc[ch][2]=0.f; pacc[ch][3]=0.f; }
    #pragma unroll
    for (int ch = 0; ch < 6; ch++) {
      int col = ch*128 + t*16 + row;
      #pragma unroll
      for (int ks = 0; ks < 4; ks++) {
        s16x8 b = *(const s16x8*)&wnt[(size_t)col*128 + ks*32 + kg*8];
        pacc[ch] = MFMA16(an[ks], b, pacc[ch]);
      }
    }
    int c = t*16 + row;
    #pragma unroll
    for (int r = 0; r < 4; r++) {
      int nc = nbase + kg*4 + r;
      size_t base = (size_t)nc*512 + c*4;
      unsigned int s0 = (unsigned int)f2bf(pacc[0][r]) | ((unsigned int)f2bf(pacc[2][r]) << 16);
      unsigned int s1 = (unsigned int)f2bf(pacc[3][r]) | ((unsigned int)f2bf(pacc[5][r]) << 16);
      unsigned int t0 = (unsigned int)f2bf(pacc[1][r]) | ((unsigned int)f2bf(pacc[2][r]) << 16);
      unsigned int t1 = (unsigned int)f2bf(pacc[4][r]) | ((unsigned int)f2bf(pacc[5][r]) << 16);
      *(uint2*)&spackb[base] = make_uint2(s0, s1);
      *(uint2*)&tpackb[base] = make_uint2(t0, t1);
    }
  }
}

// ---------------- fused edge v4: 32 edges/wave, wave-independent ----------------
__global__ __launch_bounds__(256) void fused_edge(
    float* __restrict__ h_acc,
    const unsigned short* __restrict__ csb, const unsigned short* __restrict__ pwb,
    const unsigned short* __restrict__ w1t, const unsigned short* __restrict__ w2t,
    const unsigned short* __restrict__ w2gt,
    const int* __restrict__ srcp, const int* __restrict__ tgtp,
    const float* __restrict__ edp, const int* __restrict__ nact,
    const unsigned short* __restrict__ spackb, const unsigned short* __restrict__ tpackb)
{
  __shared__ unsigned short zb[4][32][132];   // 33.8 KB; per-half gate overlays own z rows
  __shared__ int   src_s[4][32];
  __shared__ int   tgt_s[4][32];
  __shared__ float rcp_s[4][32];
  __shared__ float msk_s[4][32];

  int p0 = blockIdx.x * 128;
  if (p0 >= *nact) return;                   // fully-masked tail block

  int tid  = threadIdx.x;
  int wave = tid >> 6, lane = tid & 63;
  int row  = lane & 15, kg = lane >> 4;

  if (lane < 32) {
    int e = p0 + wave*32 + lane;
    float r = edp[e];
    rcp_s[wave][lane] = 1.0f / r;
    msk_s[wave][lane] = (r < 8.0f) ? 1.0f : 0.0f;
    src_s[wave][lane] = srcp[e];
    tgt_s[wave][lane] = tgtp[e];
  }

  #pragma unroll
  for (int hf2 = 0; hf2 < 2; hf2++) {
    unsigned short* gate = &zb[wave][hf2*16][0];   // 2 KB overlay on this half's z rows
    int pos = p0 + wave*32 + hf2*16 + row;
    s16x8 acs[2], apw[2];
    acs[0] = *(const s16x8*)&csb[(size_t)pos*64 + kg*8];
    acs[1] = *(const s16x8*)&csb[(size_t)pos*64 + 32 + kg*8];
    apw[0] = *(const s16x8*)&pwb[(size_t)pos*64 + kg*8];
    apw[1] = *(const s16x8*)&pwb[(size_t)pos*64 + 32 + kg*8];

    // phase A: S1 = pw @ W2g
    f32x4 acc1[4];
    #pragma unroll
    for (int nt = 0; nt < 4; nt++) { acc1[nt][0]=0.f; acc1[nt][1]=0.f; acc1[nt][2]=0.f; acc1[nt][3]=0.f; }
    #pragma unroll
    for (int nt = 0; nt < 4; nt++) {
      s16x8 b0 = *(const s16x8*)&w2gt[(size_t)(nt*16+row)*64 + kg*8];
      s16x8 b1 = *(const s16x8*)&w2gt[(size_t)(nt*16+row)*64 + 32 + kg*8];
      acc1[nt] = MFMA16(apw[0], b0, acc1[nt]);
      acc1[nt] = MFMA16(apw[1], b1, acc1[nt]);
    }

    // sigmoid -> wave-private gate (C-layout scatter, swizzled; local row = kg*4+r)
    #pragma unroll
    for (int nt = 0; nt < 4; nt++) {
      #pragma unroll
      for (int r = 0; r < 4; r++) {
        int grow = kg*4 + r;                 // 0..15 within half
        int gcol = nt*16 + row;
        int byt = (grow << 7) + (gcol << 1);
        byt ^= (grow & 7) << 4;
        *(unsigned short*)((char*)gate + byt) = f2bf(sigf(acc1[nt][r]));
      }
    }
    WAVE_LDS_FENCE();                        // gate writes visible to whole wave

    // read gate in A-layout (local row = row), pwg frags = pw * gate
    s16x8 apg[2];
    #pragma unroll
    for (int ks = 0; ks < 2; ks++) {
      int byt = (row << 7) + ks*64 + kg*16;
      byt ^= (row & 7) << 4;
      s16x8 g = *(s16x8*)((char*)gate + byt);
      s16x8 o;
      #pragma unroll
      for (int j = 0; j < 8; j++) {
        float v = bf2f((unsigned short)apw[ks][j]) * bf2f((unsigned short)g[j]);
        o[j] = (short)f2bf(v);
      }
      apg[ks] = o;
    }
    WAVE_LDS_FENCE();                        // gate reads retired before z overwrites

    // phase B: az = cs@W1t + pwg@W2t
    f32x4 acc2[8];
    #pragma unroll
    for (int nt = 0; nt < 8; nt++) { acc2[nt][0]=0.f; acc2[nt][1]=0.f; acc2[nt][2]=0.f; acc2[nt][3]=0.f; }
    #pragma unroll
    for (int nt = 0; nt < 8; nt++) {
      #pragma unroll
      for (int ks = 0; ks < 2; ks++) {
        s16x8 b1 = *(const s16x8*)&w1t[(size_t)(nt*16+row)*64 + ks*32 + kg*8];
        acc2[nt] = MFMA16(acs[ks], b1, acc2[nt]);
        s16x8 b2 = *(const s16x8*)&w2t[(size_t)(nt*16+row)*64 + ks*32 + kg*8];
        acc2[nt] = MFMA16(apg[ks], b2, acc2[nt]);
      }
    }

    // phase C: az -> this half's zb rows
    #pragma unroll
    for (int nt = 0; nt < 8; nt++) {
      #pragma unroll
      for (int r = 0; r < 4; r++) {
        zb[wave][hf2*16 + kg*4 + r][nt*16 + row] = f2bf(acc2[nt][r]);
      }
    }
  }
  WAVE_LDS_FENCE();                          // z + metadata visible to whole wave

  // phase D: wave's 32 edges, batches of 4
  {
    int l = lane;
    int cur = src_s[wave][0];
    s16x8 sp = *(const s16x8*)&spackb[(size_t)cur*512 + l*8];
    float Ags0 = bf2f((unsigned short)sp[0]), Cgs0 = bf2f((unsigned short)sp[1]);
    float Ams0 = bf2f((unsigned short)sp[2]), Cms0 = bf2f((unsigned short)sp[3]);
    float Ags1 = bf2f((unsigned short)sp[4]), Cgs1 = bf2f((unsigned short)sp[5]);
    float Ams1 = bf2f((unsigned short)sp[6]), Cms1 = bf2f((unsigned short)sp[7]);
    float acc0 = 0.f, accB = 0.f;
    for (int eb = 0; eb < 32; eb += 4) {
      s16x8 tp[4]; unsigned int zz[4];
      #pragma unroll
      for (int b = 0; b < 4; b++) {
        int e = eb + b;
        tp[b] = *(const s16x8*)&tpackb[(size_t)tgt_s[wave][e]*512 + l*8];
        zz[b] = *(const unsigned int*)&zb[wave][e][2*l];
      }
      #pragma unroll
      for (int b = 0; b < 4; b++) {
        int e = eb + b;
        int sn = src_s[wave][e];
        if (sn != cur) {   // wave-uniform (src-sorted)
          atomicAdd(&h_acc[(size_t)cur*H + 2*l],     acc0);
          atomicAdd(&h_acc[(size_t)cur*H + 2*l + 1], accB);
          acc0 = 0.f; accB = 0.f; cur = sn;
          sp = *(const s16x8*)&spackb[(size_t)cur*512 + l*8];
          Ags0 = bf2f((unsigned short)sp[0]); Cgs0 = bf2f((unsigned short)sp[1]);
          Ams0 = bf2f((unsigned short)sp[2]); Cms0 = bf2f((unsigned short)sp[3]);
          Ags1 = bf2f((unsigned short)sp[4]); Cgs1 = bf2f((unsigned short)sp[5]);
          Ams1 = bf2f((unsigned short)sp[6]); Cms1 = bf2f((unsigned short)sp[7]);
        }
        float rc = rcp_s[wave][e], mk = msk_s[wave][e];
        float z0 = bf2f((unsigned short)(zz[b] & 0xffffu));
        float z1 = bf2f((unsigned short)(zz[b] >> 16));
        float Bg0 = bf2f((unsigned short)tp[b][0]), Cg0 = bf2f((unsigned short)tp[b][1]);
        float Bm0 = bf2f((unsigned short)tp[b][2]), Cm0 = bf2f((unsigned short)tp[b][3]);
        float Bg1 = bf2f((unsigned short)tp[b][4]), Cg1 = bf2f((unsigned short)tp[b][5]);
        float Bm1 = bf2f((unsigned short)tp[b][6]), Cm1 = bf2f((unsigned short)tp[b][7]);
        float g0 = sigf(Ags0 + Bg0 + rc*(Cgs0 - Cg0));
        float m0 = eluf(Ams0 + Bm0 + rc*(Cms0 - Cm0));
        acc0 += g0 * m0 * z0 * mk;
        float g1 = sigf(Ags1 + Bg1 + rc*(Cgs1 - Cg1));
        float m1 = eluf(Ams1 + Bm1 + rc*(Cms1 - Cm1));
        accB += g1 * m1 * z1 * mk;
      }
    }
    atomicAdd(&h_acc[(size_t)cur*H + 2*l],     acc0);
    atomicAdd(&h_acc[(size_t)cur*H + 2*l + 1], accB);
  }
}

// ---------------- node_next v2: 16 nodes/block, 8 waves (512 thr) ----------------
__global__ __launch_bounds__(512) void node_next(
    float* __restrict__ h,                       // in/out (in-place update)
    const unsigned short* __restrict__ wpt,      // this layer p1/p2/psi
    const unsigned short* __restrict__ wnt,      // NEXT layer Wg/Wm
    const int* __restrict__ gidx, float* __restrict__ pooled,
    unsigned short* __restrict__ spackb, unsigned short* __restrict__ tpackb,
    int has_next)
{
  __shared__ unsigned short hb[16*128];          // 4 KB swizzled bf16 h_next
  int tid = threadIdx.x, wave = tid >> 6, lane = tid & 63;
  int row = lane & 15, kg = lane >> 4;
  int nbase = blockIdx.x*16;
  const float* hr = &h[(size_t)(nbase + row)*H];
  s16x8 a[4];
  #pragma unroll
  for (int ks = 0; ks < 4; ks++) a[ks] = loadA_f32(hr + ks*32 + kg*8);
  __syncthreads();   // RACE FIX: all waves' h reads complete before any wave writes h in-place

  // psi/pool phase: wave owns col-tile = wave (16 cols)
  int col = wave*16 + row;
  f32x4 acc1, acc2, acc3;
  acc1[0]=0.f; acc1[1]=0.f; acc1[2]=0.f; acc1[3]=0.f;
  acc2 = acc1; acc3 = acc1;
  #pragma unroll
  for (int ks = 0; ks < 4; ks++) {
    s16x8 b1 = *(const s16x8*)&wpt[(size_t)(col      )*128 + ks*32 + kg*8];
    s16x8 b2 = *(const s16x8*)&wpt[(size_t)(col + 128)*128 + ks*32 + kg*8];
    s16x8 b3 = *(const s16x8*)&wpt[(size_t)(col + 256)*128 + ks*32 + kg*8];
    acc1 = MFMA16(a[ks], b1, acc1);
    acc2 = MFMA16(a[ks], b2, acc2);
    acc3 = MFMA16(a[ks], b3, acc3);
  }

  int nc0 = nbase + kg*4;
  int g0 = gidx[nc0], g3 = gidx[nc0 + 3];
  if (g0 == g3) {
    float s = 0.f;
    #pragma unroll
    for (int r = 0; r < 4; r++) s += eluf(acc1[r] * acc2[r]);
    atomicAdd(&pooled[g0*H + col], s);
    #pragma unroll
    for (int r = 0; r < 4; r++) {
      int ln = kg*4 + r;
      float v = eluf(acc3[r]);
      h[(size_t)(nc0 + r)*H + col] = v;
      int byt = (ln << 8) + (col << 1);
      byt ^= (ln & 7) << 4;
      *(unsigned short*)((char*)hb + byt) = f2bf(v);
    }
  } else {
    #pragma unroll
    for (int r = 0; r < 4; r++) {
      int nc = nc0 + r;
      int ln = kg*4 + r;
      int g = gidx[nc];
      float zp = eluf(acc1[r] * acc2[r]);
      atomicAdd(&pooled[g*H + col], zp);
      float v = eluf(acc3[r]);
      h[(size_t)nc*H + col] = v;
      int byt = (ln << 8) + (col << 1);
      byt ^= (ln & 7) << 4;
      *(unsigned short*)((char*)hb + byt) = f2bf(v);
    }
  }
  if (!has_next) return;
  __syncthreads();

  // pack GEMM from LDS h_next; wave owns c-tile = wave; all 6 chunks; 8B stores
  s16x8 an[4];
  #pragma unroll
  for (int ks = 0; ks < 4; ks++) {
    int byt = (row << 8) + ks*64 + kg*16;
    byt ^= (row & 7) << 4;
    an[ks] = *(s16x8*)((char*)hb + byt);
  }
  f32x4 pacc[6];
  #pragma unroll
  for (int ch = 0; ch < 6; ch++) { pacc[ch][0]=0.f; pacc[ch][1]=0.f; pacc[ch][2]=0.f; pacc[ch][3]=0.f; }
  #pragma unroll
  for (int ch = 0; ch < 6; ch++) {
    int pcol = ch*128 + wave*16 + row;
    #pragma unroll
    for (int ks = 0; ks < 4; ks++) {
      s16x8 b = *(const s16x8*)&wnt[(size_t)pcol*128 + ks*32 + kg*8];
      pacc[ch] = MFMA16(an[ks], b, pacc[ch]);
    }
  }
  int c = wave*16 + row;
  #pragma unroll
  for (int r = 0; r < 4; r++) {
    int nc = nbase + kg*4 + r;
    size_t base = (size_t)nc*512 + c*4;
    unsigned int s0 = (unsigned int)f2bf(pacc[0][r]) | ((unsigned int)f2bf(pacc[2][r]) << 16);
    unsigned int s1 = (unsigned int)f2bf(pacc[3][r]) | ((unsigned int)f2bf(pacc[5][r]) << 16);
    unsigned int t0 = (unsigned int)f2bf(pacc[1][r]) | ((unsigned int)f2bf(pacc[2][r]) << 16);
    unsigned int t1 = (unsigned int)f2bf(pacc[4][r]) | ((unsigned int)f2bf(pacc[5][r]) << 16);
    *(uint2*)&spackb[base] = make_uint2(s0, s1);
    *(uint2*)&tpackb[base] = make_uint2(t0, t1);
  }
}

// ---------------- final: y = elu(elu(pooled @ lr1) @ lr2) ----------------
__global__ __launch_bounds__(64) void final_kernel(
    const float* __restrict__ pooled, const float* __restrict__ lr1, const float* __restrict__ lr2,
    float* __restrict__ out)
{
  __shared__ float sp[128];
  __shared__ float y1[64];
  int g = blockIdx.x, tid = threadIdx.x;
  sp[tid]      = pooled[g*128 + tid];
  sp[tid + 64] = pooled[g*128 + 64 + tid];
  __syncthreads();
  float acc = 0.f;
  for (int k = 0; k < 128; k++) acc += sp[k] * lr1[k*64 + tid];
  y1[tid] = eluf(acc);
  __syncthreads();
  if (tid < 32) {
    float a2 = 0.f;
    for (int k = 0; k < 64; k++) a2 += y1[k] * lr2[k*32 + tid];
    out[g*32 + tid] = eluf(a2);
  }
}

extern "C" void kernel_launch(void* const* d_in, const int* in_sizes, int n_in,
                              void* d_out, int out_size, void* d_ws, size_t ws_size,
                              hipStream_t stream)
{
  const float* x    = (const float*)d_in[0];
  const float* ed   = (const float*)d_in[1];
  const float* cs   = (const float*)d_in[2];
  const float* pw   = (const float*)d_in[3];
  const float* embW = (const float*)d_in[4];
  const float* Wg   = (const float*)d_in[5];
  const float* Wm   = (const float*)d_in[6];
  const float* W1   = (const float*)d_in[7];
  const float* W2g  = (const float*)d_in[8];
  const float* W2   = (const float*)d_in[9];
  const float* p1   = (const float*)d_in[10];
  const float* p2   = (const float*)d_in[11];
  const float* psiW = (const float*)d_in[12];
  const float* lr1  = (const float*)d_in[13];
  const float* lr2  = (const float*)d_in[14];
  const int* esrc   = (const int*)d_in[15];
  const int* etgt   = (const int*)d_in[16];
  const int* gidx   = (const int*)d_in[17];

  float* h_b    = (float*)d_ws;                 // 1,280,000 f
  float* pooled = h_b + (size_t)N_NODES*H;      // 12,800 f
  unsigned short* spackb = (unsigned short*)(pooled + 100*H); // N_NODES*512 us
  unsigned short* tpackb = spackb + (size_t)N_NODES*512;      // N_NODES*512 us
  int* counts  = (int*)(tpackb + (size_t)N_NODES*512);
  int* offsets = counts + N_NODES;              // N_NODES+1 (offsets[N_NODES] = n_active)
  int* cursor  = offsets + N_NODES + 1;
  int* mcur    = cursor + N_NODES;              // 1
  int* perm    = mcur + 1;                      // N_EDGES
  int* srcp    = perm + N_EDGES;                // N_EDGES
  int* tgtp    = srcp + N_EDGES;                // N_EDGES
  float* edp   = (float*)(tgtp + N_EDGES);      // N_EDGES
  unsigned short* w1t  = (unsigned short*)(edp + N_EDGES); // 3*8192
  unsigned short* w2t  = w1t + 3*8192;
  unsigned short* w2gt = w2t + 3*8192;          // 3*4096
  unsigned short* embt = w2gt + 3*4096;         // 16384
  unsigned short* wnt  = embt + 16384;          // 3*98304
  unsigned short* wpt  = wnt + 3*98304;         // 3*49152
  unsigned short* csb  = wpt + 3*49152;         // N_EDGES*64
  unsigned short* pwb  = csb + (size_t)N_EDGES*64; // N_EDGES*64

  // one-time: edge sort by (masked, src) + de-indirect + bf16 conversions
  hipMemsetAsync(counts, 0, N_NODES*sizeof(int), stream);
  hipMemsetAsync(mcur, 0, sizeof(int), stream);
  hipMemsetAsync(pooled, 0, 100*H*sizeof(float), stream);
  hist_kernel<<<(N_EDGES+255)/256, 256, 0, stream>>>(esrc, ed, counts);
  scan_kernel<<<1, 256, 0, stream>>>(counts, offsets);
  hipMemcpyAsync(cursor, offsets, N_NODES*sizeof(int), hipMemcpyDeviceToDevice, stream);
  scatter_kernel<<<(N_EDGES+255)/256, 256, 0, stream>>>(esrc, etgt, ed, offsets,
      cursor, mcur, perm, srcp, tgtp, edp);
  prep_edges<<<N_EDGES*8/256, 256, 0, stream>>>(cs, pw, perm, offsets + N_NODES, csb, pwb);
  prep_weights<<<208, 256, 0, stream>>>(W1, W2, W2g, embW, w1t, w2t, w2gt, embt);
  prep_nodew<<<(3*98304 + 3*49152 + 255)/256, 256, 0, stream>>>(Wg, Wm, p1, p2, psiW, wnt, wpt);

  embed_pack<<<N_NODES/16, 256, 0, stream>>>(x, embt, wnt, h_b, spackb, tpackb);

  for (int i = 0; i < 3; i++) {
    fused_edge<<<N_EDGES/128, 256, 0, stream>>>(h_b, csb, pwb,
        w1t + i*8192, w2t + i*8192, w2gt + i*4096,
        srcp, tgtp, edp, offsets + N_NODES, spackb, tpackb);
    node_next<<<N_NODES/16, 512, 0, stream>>>(h_b,
        wpt + i*49152, wnt + ((i+1) % 3)*98304,
        gidx, pooled, spackb, tpackb, (i < 2) ? 1 : 0);
  }
  final_kernel<<<100, 64, 0, stream>>>(pooled, lr1, lr2, (float*)d_out);
}

// Round 15
// 426.835 us; speedup vs baseline: 1.0810x; 1.0810x over previous
//
#include <hip/hip_runtime.h>
#include <math.h>

#define H 128
#define N_NODES 10000
#define N_EDGES 160000

typedef float f32x4 __attribute__((ext_vector_type(4)));
typedef short s16x8 __attribute__((ext_vector_type(8)));

#define WAVE_LDS_FENCE() do { \
  asm volatile("s_waitcnt lgkmcnt(0)" ::: "memory"); \
  __builtin_amdgcn_sched_barrier(0); \
} while (0)

__device__ __forceinline__ float sigf(float x){ return 1.0f/(1.0f + __expf(-x)); }
__device__ __forceinline__ float eluf(float x){ return x > 0.0f ? x : (__expf(x) - 1.0f); }

__device__ __forceinline__ unsigned short f2bf(float f){
  unsigned int u = __float_as_uint(f);
  unsigned int r = (u + 0x7fffu + ((u >> 16) & 1u)) >> 16;
  return (unsigned short)r;
}
__device__ __forceinline__ float bf2f(unsigned short s){
  return __uint_as_float(((unsigned int)s) << 16);
}

__device__ __forceinline__ f32x4 MFMA16(s16x8 a, s16x8 b, f32x4 c){
  return __builtin_amdgcn_mfma_f32_16x16x32_bf16(a, b, c, 0, 0, 0);
}

__device__ __forceinline__ s16x8 loadA_f32(const float* p){
  float4 a = *(const float4*)p;
  float4 b = *(const float4*)(p+4);
  s16x8 r;
  r[0]=(short)f2bf(a.x); r[1]=(short)f2bf(a.y); r[2]=(short)f2bf(a.z); r[3]=(short)f2bf(a.w);
  r[4]=(short)f2bf(b.x); r[5]=(short)f2bf(b.y); r[6]=(short)f2bf(b.z); r[7]=(short)f2bf(b.w);
  return r;
}

// ---------------- edge sort by (masked, src): hist(active) -> scan -> scatter ----------------
__global__ __launch_bounds__(256) void hist_kernel(
    const int* __restrict__ src, const float* __restrict__ ed, int* __restrict__ count)
{
  int e = blockIdx.x*256 + threadIdx.x;
  if (e < N_EDGES && ed[e] < 8.0f) atomicAdd(&count[src[e]], 1);
}

__global__ __launch_bounds__(256) void scan_kernel(
    const int* __restrict__ count, int* __restrict__ offsets)
{
  __shared__ int tmp[256];
  __shared__ int sbase;
  if (threadIdx.x == 0) sbase = 0;
  __syncthreads();
  for (int c0 = 0; c0 < N_NODES; c0 += 256) {
    int i = c0 + threadIdx.x;
    int v = (i < N_NODES) ? count[i] : 0;
    tmp[threadIdx.x] = v;
    __syncthreads();
    for (int off = 1; off < 256; off <<= 1) {
      int t = (threadIdx.x >= off) ? tmp[threadIdx.x - off] : 0;
      __syncthreads();
      tmp[threadIdx.x] += t;
      __syncthreads();
    }
    if (i < N_NODES) offsets[i] = sbase + tmp[threadIdx.x] - v;
    __syncthreads();
    if (threadIdx.x == 255) sbase += tmp[255];
    __syncthreads();
  }
  if (threadIdx.x == 0) offsets[N_NODES] = sbase;   // n_active
}

__global__ __launch_bounds__(256) void scatter_kernel(
    const int* __restrict__ src, const int* __restrict__ tgt, const float* __restrict__ ed,
    const int* __restrict__ offsets,
    int* __restrict__ cursor, int* __restrict__ mcur, int* __restrict__ perm,
    int* __restrict__ srcp, int* __restrict__ tgtp, float* __restrict__ edp)
{
  int e = blockIdx.x*256 + threadIdx.x;
  if (e < N_EDGES) {
    int s = src[e];
    float r = ed[e];
    int pos;
    if (r < 8.0f) pos = atomicAdd(&cursor[s], 1);
    else          pos = offsets[N_NODES] + atomicAdd(mcur, 1);
    perm[pos] = e;
    srcp[pos] = s;
    tgtp[pos] = tgt[e];
    edp[pos]  = r;
  }
}

// ---------------- prep_edges: permuted bf16 copies of cs, pw (zeros past n_active) ----------------
__global__ __launch_bounds__(256) void prep_edges(
    const float* __restrict__ cs, const float* __restrict__ pw, const int* __restrict__ perm,
    const int* __restrict__ nact,
    unsigned short* __restrict__ csb, unsigned short* __restrict__ pwb)
{
  int idx = blockIdx.x*256 + threadIdx.x;   // over N_EDGES*8
  if (idx >= N_EDGES*8) return;
  int pos = idx >> 3, kc = idx & 7;
  if (pos < *nact) {
    int e = perm[pos];
    s16x8 c = loadA_f32(&cs[(size_t)e*64 + kc*8]);
    s16x8 p = loadA_f32(&pw[(size_t)e*64 + kc*8]);
    *(s16x8*)&csb[(size_t)pos*64 + kc*8] = c;
    *(s16x8*)&pwb[(size_t)pos*64 + kc*8] = p;
  } else {
    s16x8 z = {0,0,0,0,0,0,0,0};
    *(s16x8*)&csb[(size_t)pos*64 + kc*8] = z;
    *(s16x8*)&pwb[(size_t)pos*64 + kc*8] = z;
  }
}

// ---------------- prep_weights: W1,W2,W2g,embW -> bf16 [col][k] ----------------
__global__ __launch_bounds__(256) void prep_weights(
    const float* __restrict__ W1, const float* __restrict__ W2, const float* __restrict__ W2g,
    const float* __restrict__ embW,
    unsigned short* __restrict__ w1t, unsigned short* __restrict__ w2t,
    unsigned short* __restrict__ w2gt, unsigned short* __restrict__ embt)
{
  int idx = blockIdx.x*256 + threadIdx.x;
  if (idx < 3*8192) {
    int l = idx / 8192, r = idx % 8192;
    int c = r >> 6, k = r & 63;
    w1t[idx] = f2bf(W1[l*8192 + k*128 + c]);
    w2t[idx] = f2bf(W2[l*8192 + k*128 + c]);
  } else if (idx < 3*8192 + 3*4096) {
    int idx2 = idx - 3*8192;
    int l = idx2 / 4096, r = idx2 % 4096;
    int c = r >> 6, k = r & 63;
    w2gt[idx2] = f2bf(W2g[l*4096 + k*64 + c]);
  } else {
    int idx3 = idx - (3*8192 + 3*4096);
    if (idx3 < 16384) {
      int c = idx3 >> 7, k = idx3 & 127;
      embt[idx3] = f2bf(embW[k*128 + c]);
    }
  }
}

// ---------------- prep_nodew: bf16 [col][k] transposes for node GEMMs ----------------
__global__ __launch_bounds__(256) void prep_nodew(
    const float* __restrict__ Wg, const float* __restrict__ Wm,
    const float* __restrict__ p1, const float* __restrict__ p2, const float* __restrict__ psiW,
    unsigned short* __restrict__ wnt, unsigned short* __restrict__ wpt)
{
  int idx = blockIdx.x*256 + threadIdx.x;
  if (idx < 3*98304) {
    int l = idx / 98304, r = idx % 98304;
    int j = r >> 7, k = r & 127;
    float v;
    if (j < 384) v = Wg[l*49152 + (j>>7)*16384 + k*128 + (j&127)];
    else { int jj = j - 384; v = Wm[l*49152 + (jj>>7)*16384 + k*128 + (jj&127)]; }
    wnt[idx] = f2bf(v);
  } else {
    int idx2 = idx - 3*98304;
    if (idx2 < 3*49152) {
      int l = idx2 / 49152, r = idx2 % 49152;
      int j = r >> 7, k = r & 127;
      float v;
      if (j < 128)      v = p1 [l*16384 + k*128 + j];
      else if (j < 256) v = p2 [l*16384 + k*128 + (j-128)];
      else              v = psiW[l*16384 + k*128 + (j-256)];
      wpt[idx2] = f2bf(v);
    }
  }
}

// ---------------- embed_pack: h = sig(x@embW) + layer-0 pack GEMM, 16 nodes/block ----------------
__global__ __launch_bounds__(256) void embed_pack(
    const float* __restrict__ x, const unsigned short* __restrict__ embt,
    const unsigned short* __restrict__ wnt,
    float* __restrict__ h_out,
    unsigned short* __restrict__ spackb, unsigned short* __restrict__ tpackb)
{
  __shared__ unsigned short hb[16*128];          // 4 KB swizzled bf16 h
  int tid = threadIdx.x, wave = tid >> 6, lane = tid & 63;
  int row = lane & 15, kg = lane >> 4;
  int nbase = blockIdx.x*16;
  const float* xr = &x[(size_t)(nbase + row)*H];
  s16x8 a[4];
  #pragma unroll
  for (int ks = 0; ks < 4; ks++) a[ks] = loadA_f32(xr + ks*32 + kg*8);

  f32x4 acc[2];
  #pragma unroll
  for (int ti = 0; ti < 2; ti++) { acc[ti][0]=0.f; acc[ti][1]=0.f; acc[ti][2]=0.f; acc[ti][3]=0.f; }
  #pragma unroll
  for (int ti = 0; ti < 2; ti++) {
    int col = (wave*2 + ti)*16 + row;
    #pragma unroll
    for (int ks = 0; ks < 4; ks++) {
      s16x8 b = *(const s16x8*)&embt[(size_t)col*128 + ks*32 + kg*8];
      acc[ti] = MFMA16(a[ks], b, acc[ti]);
    }
  }
  #pragma unroll
  for (int ti = 0; ti < 2; ti++) {
    int col = (wave*2 + ti)*16 + row;
    #pragma unroll
    for (int r = 0; r < 4; r++) {
      int ln = kg*4 + r;
      float v = sigf(acc[ti][r]);
      h_out[(size_t)(nbase + ln)*H + col] = v;
      int byt = (ln << 8) + (col << 1);
      byt ^= (ln & 7) << 4;
      *(unsigned short*)((char*)hb + byt) = f2bf(v);
    }
  }
  __syncthreads();

  // pack GEMM from LDS
  s16x8 an[4];
  #pragma unroll
  for (int ks = 0; ks < 4; ks++) {
    int byt = (row << 8) + ks*64 + kg*16;
    byt ^= (row & 7) << 4;
    an[ks] = *(s16x8*)((char*)hb + byt);
  }
  #pragma unroll
  for (int ti = 0; ti < 2; ti++) {
    int t = wave*2 + ti;
    f32x4 pacc[6];
    #pragma unroll
    for (int ch = 0; ch < 6; ch++) { pacc[ch][0]=0.f; pacc[ch][1]=0.f; pacc[ch][2]=0.f; pacc[ch][3]=0.f; }
    #pragma unroll
    for (int ch = 0; ch < 6; ch++) {
      int col = ch*128 + t*16 + row;
      #pragma unroll
      for (int ks = 0; ks < 4; ks++) {
        s16x8 b = *(const s16x8*)&wnt[(size_t)col*128 + ks*32 + kg*8];
        pacc[ch] = MFMA16(an[ks], b, pacc[ch]);
      }
    }
    int c = t*16 + row;
    #pragma unroll
    for (int r = 0; r < 4; r++) {
      int nc = nbase + kg*4 + r;
      size_t base = (size_t)nc*512 + c*4;
      unsigned int s0 = (unsigned int)f2bf(pacc[0][r]) | ((unsigned int)f2bf(pacc[2][r]) << 16);
      unsigned int s1 = (unsigned int)f2bf(pacc[3][r]) | ((unsigned int)f2bf(pacc[5][r]) << 16);
      unsigned int t0 = (unsigned int)f2bf(pacc[1][r]) | ((unsigned int)f2bf(pacc[2][r]) << 16);
      unsigned int t1 = (unsigned int)f2bf(pacc[4][r]) | ((unsigned int)f2bf(pacc[5][r]) << 16);
      *(uint2*)&spackb[base] = make_uint2(s0, s1);
      *(uint2*)&tpackb[base] = make_uint2(t0, t1);
    }
  }
}

// ---------------- fused edge (R12 structure): 16 edges/wave, wave-independent ----------------
// Mask multiply removed: tail positions (>= n_active) have zeroed csb/pwb -> z = 0.
__global__ __launch_bounds__(256) void fused_edge(
    float* __restrict__ h_acc,
    const unsigned short* __restrict__ csb, const unsigned short* __restrict__ pwb,
    const unsigned short* __restrict__ w1t, const unsigned short* __restrict__ w2t,
    const unsigned short* __restrict__ w2gt,
    const int* __restrict__ srcp, const int* __restrict__ tgtp,
    const float* __restrict__ edp, const int* __restrict__ nact,
    const unsigned short* __restrict__ spackb, const unsigned short* __restrict__ tpackb)
{
  __shared__ unsigned short zb[4][16][132];   // per-wave 4224 B slice; first 2 KB doubles as gate
  __shared__ int   src_s[4][16];
  __shared__ int   tgt_s[4][16];
  __shared__ float rcp_s[4][16];

  int p0 = blockIdx.x * 64;
  if (p0 >= *nact) return;                   // fully-masked tail block

  int tid  = threadIdx.x;
  int wave = tid >> 6, lane = tid & 63;
  int row  = lane & 15, kg = lane >> 4;
  unsigned short* gate = &zb[wave][0][0];    // wave-private 2 KB overlay

  if (lane < 16) {
    int e = p0 + wave*16 + lane;
    rcp_s[wave][lane] = 1.0f / edp[e];
    src_s[wave][lane] = srcp[e];
    tgt_s[wave][lane] = tgtp[e];
  }

  int pos = p0 + wave*16 + row;
  s16x8 acs[2], apw[2];
  acs[0] = *(const s16x8*)&csb[(size_t)pos*64 + kg*8];
  acs[1] = *(const s16x8*)&csb[(size_t)pos*64 + 32 + kg*8];
  apw[0] = *(const s16x8*)&pwb[(size_t)pos*64 + kg*8];
  apw[1] = *(const s16x8*)&pwb[(size_t)pos*64 + 32 + kg*8];

  // phase A: S1 = pw @ W2g
  f32x4 acc1[4];
  #pragma unroll
  for (int nt = 0; nt < 4; nt++) { acc1[nt][0]=0.f; acc1[nt][1]=0.f; acc1[nt][2]=0.f; acc1[nt][3]=0.f; }
  #pragma unroll
  for (int nt = 0; nt < 4; nt++) {
    s16x8 b0 = *(const s16x8*)&w2gt[(size_t)(nt*16+row)*64 + kg*8];
    s16x8 b1 = *(const s16x8*)&w2gt[(size_t)(nt*16+row)*64 + 32 + kg*8];
    acc1[nt] = MFMA16(apw[0], b0, acc1[nt]);
    acc1[nt] = MFMA16(apw[1], b1, acc1[nt]);
  }

  // sigmoid -> wave-private gate (C-layout scatter, swizzled; local row = kg*4+r)
  #pragma unroll
  for (int nt = 0; nt < 4; nt++) {
    #pragma unroll
    for (int r = 0; r < 4; r++) {
      int grow = kg*4 + r;                   // 0..15 within wave
      int gcol = nt*16 + row;
      int byt = (grow << 7) + (gcol << 1);
      byt ^= (grow & 7) << 4;
      *(unsigned short*)((char*)gate + byt) = f2bf(sigf(acc1[nt][r]));
    }
  }
  WAVE_LDS_FENCE();                          // gate writes visible to whole wave

  // read gate in A-layout (local row = row), pwg frags = pw * gate
  s16x8 apg[2];
  #pragma unroll
  for (int ks = 0; ks < 2; ks++) {
    int byt = (row << 7) + ks*64 + kg*16;
    byt ^= (row & 7) << 4;
    s16x8 g = *(s16x8*)((char*)gate + byt);
    s16x8 o;
    #pragma unroll
    for (int j = 0; j < 8; j++) {
      float v = bf2f((unsigned short)apw[ks][j]) * bf2f((unsigned short)g[j]);
      o[j] = (short)f2bf(v);
    }
    apg[ks] = o;
  }
  WAVE_LDS_FENCE();                          // gate reads retired before zb overwrites

  // phase B: az = cs@W1t + pwg@W2t
  f32x4 acc2[8];
  #pragma unroll
  for (int nt = 0; nt < 8; nt++) { acc2[nt][0]=0.f; acc2[nt][1]=0.f; acc2[nt][2]=0.f; acc2[nt][3]=0.f; }
  #pragma unroll
  for (int nt = 0; nt < 8; nt++) {
    #pragma unroll
    for (int ks = 0; ks < 2; ks++) {
      s16x8 b1 = *(const s16x8*)&w1t[(size_t)(nt*16+row)*64 + ks*32 + kg*8];
      acc2[nt] = MFMA16(acs[ks], b1, acc2[nt]);
      s16x8 b2 = *(const s16x8*)&w2t[(size_t)(nt*16+row)*64 + ks*32 + kg*8];
      acc2[nt] = MFMA16(apg[ks], b2, acc2[nt]);
    }
  }

  // phase C: az -> wave-private zb (local edge row = kg*4+r)
  #pragma unroll
  for (int nt = 0; nt < 8; nt++) {
    #pragma unroll
    for (int r = 0; r < 4; r++) {
      zb[wave][kg*4 + r][nt*16 + row] = f2bf(acc2[nt][r]);
    }
  }
  WAVE_LDS_FENCE();                          // zb + metadata visible to whole wave

  // phase D: wave's 16 edges, batches of 4
  {
    int l = lane;
    int cur = src_s[wave][0];
    s16x8 sp = *(const s16x8*)&spackb[(size_t)cur*512 + l*8];
    float Ags0 = bf2f((unsigned short)sp[0]), Cgs0 = bf2f((unsigned short)sp[1]);
    float Ams0 = bf2f((unsigned short)sp[2]), Cms0 = bf2f((unsigned short)sp[3]);
    float Ags1 = bf2f((unsigned short)sp[4]), Cgs1 = bf2f((unsigned short)sp[5]);
    float Ams1 = bf2f((unsigned short)sp[6]), Cms1 = bf2f((unsigned short)sp[7]);
    float acc0 = 0.f, accB = 0.f;
    for (int eb = 0; eb < 16; eb += 4) {
      s16x8 tp[4]; unsigned int zz[4];
      #pragma unroll
      for (int b = 0; b < 4; b++) {
        int e = eb + b;
        tp[b] = *(const s16x8*)&tpackb[(size_t)tgt_s[wave][e]*512 + l*8];
        zz[b] = *(const unsigned int*)&zb[wave][e][2*l];
      }
      #pragma unroll
      for (int b = 0; b < 4; b++) {
        int e = eb + b;
        int sn = src_s[wave][e];
        if (sn != cur) {   // wave-uniform (src-sorted)
          atomicAdd(&h_acc[(size_t)cur*H + 2*l],     acc0);
          atomicAdd(&h_acc[(size_t)cur*H + 2*l + 1], accB);
          acc0 = 0.f; accB = 0.f; cur = sn;
          sp = *(const s16x8*)&spackb[(size_t)cur*512 + l*8];
          Ags0 = bf2f((unsigned short)sp[0]); Cgs0 = bf2f((unsigned short)sp[1]);
          Ams0 = bf2f((unsigned short)sp[2]); Cms0 = bf2f((unsigned short)sp[3]);
          Ags1 = bf2f((unsigned short)sp[4]); Cgs1 = bf2f((unsigned short)sp[5]);
          Ams1 = bf2f((unsigned short)sp[6]); Cms1 = bf2f((unsigned short)sp[7]);
        }
        float rc = rcp_s[wave][e];
        float z0 = bf2f((unsigned short)(zz[b] & 0xffffu));
        float z1 = bf2f((unsigned short)(zz[b] >> 16));
        float Bg0 = bf2f((unsigned short)tp[b][0]), Cg0 = bf2f((unsigned short)tp[b][1]);
        float Bm0 = bf2f((unsigned short)tp[b][2]), Cm0 = bf2f((unsigned short)tp[b][3]);
        float Bg1 = bf2f((unsigned short)tp[b][4]), Cg1 = bf2f((unsigned short)tp[b][5]);
        float Bm1 = bf2f((unsigned short)tp[b][6]), Cm1 = bf2f((unsigned short)tp[b][7]);
        float g0 = sigf(Ags0 + Bg0 + rc*(Cgs0 - Cg0));
        float m0 = eluf(Ams0 + Bm0 + rc*(Cms0 - Cm0));
        acc0 += g0 * m0 * z0;
        float g1 = sigf(Ags1 + Bg1 + rc*(Cgs1 - Cg1));
        float m1 = eluf(Ams1 + Bm1 + rc*(Cms1 - Cm1));
        accB += g1 * m1 * z1;
      }
    }
    atomicAdd(&h_acc[(size_t)cur*H + 2*l],     acc0);
    atomicAdd(&h_acc[(size_t)cur*H + 2*l + 1], accB);
  }
}

// ---------------- node_next (R12 structure + race fix): 16 nodes/block, 4 waves ----------------
__global__ __launch_bounds__(256) void node_next(
    float* __restrict__ h,                       // in/out (in-place update)
    const unsigned short* __restrict__ wpt,      // this layer p1/p2/psi
    const unsigned short* __restrict__ wnt,      // NEXT layer Wg/Wm
    const int* __restrict__ gidx, float* __restrict__ pooled,
    unsigned short* __restrict__ spackb, unsigned short* __restrict__ tpackb,
    int has_next)
{
  __shared__ unsigned short hb[16*128];          // 4 KB swizzled bf16 h_next
  int tid = threadIdx.x, wave = tid >> 6, lane = tid & 63;
  int row = lane & 15, kg = lane >> 4;
  int nbase = blockIdx.x*16;
  const float* hr = &h[(size_t)(nbase + row)*H];
  s16x8 a[4];
  #pragma unroll
  for (int ks = 0; ks < 4; ks++) a[ks] = loadA_f32(hr + ks*32 + kg*8);
  __syncthreads();   // RACE FIX: all waves' h reads complete before any wave writes h in-place

  f32x4 acc1[2], acc2[2], acc3[2];
  #pragma unroll
  for (int ti = 0; ti < 2; ti++) {
    #pragma unroll
    for (int r = 0; r < 4; r++) { acc1[ti][r]=0.f; acc2[ti][r]=0.f; acc3[ti][r]=0.f; }
  }
  #pragma unroll
  for (int ti = 0; ti < 2; ti++) {
    int col = (wave*2 + ti)*16 + row;
    #pragma unroll
    for (int ks = 0; ks < 4; ks++) {
      s16x8 b1 = *(const s16x8*)&wpt[(size_t)(col      )*128 + ks*32 + kg*8];
      s16x8 b2 = *(const s16x8*)&wpt[(size_t)(col + 128)*128 + ks*32 + kg*8];
      s16x8 b3 = *(const s16x8*)&wpt[(size_t)(col + 256)*128 + ks*32 + kg*8];
      acc1[ti] = MFMA16(a[ks], b1, acc1[ti]);
      acc2[ti] = MFMA16(a[ks], b2, acc2[ti]);
      acc3[ti] = MFMA16(a[ks], b3, acc3[ti]);
    }
  }

  int nc0 = nbase + kg*4;
  int g0 = gidx[nc0], g3 = gidx[nc0 + 3];
  if (g0 == g3) {
    #pragma unroll
    for (int ti = 0; ti < 2; ti++) {
      int col = (wave*2 + ti)*16 + row;
      float s = 0.f;
      #pragma unroll
      for (int r = 0; r < 4; r++) s += eluf(acc1[ti][r] * acc2[ti][r]);
      atomicAdd(&pooled[g0*H + col], s);
      #pragma unroll
      for (int r = 0; r < 4; r++) {
        int ln = kg*4 + r;
        float v = eluf(acc3[ti][r]);
        h[(size_t)(nc0 + r)*H + col] = v;
        int byt = (ln << 8) + (col << 1);
        byt ^= (ln & 7) << 4;
        *(unsigned short*)((char*)hb + byt) = f2bf(v);
      }
    }
  } else {
    #pragma unroll
    for (int r = 0; r < 4; r++) {
      int nc = nc0 + r;
      int ln = kg*4 + r;
      int g = gidx[nc];
      #pragma unroll
      for (int ti = 0; ti < 2; ti++) {
        int col = (wave*2 + ti)*16 + row;
        float zp = eluf(acc1[ti][r] * acc2[ti][r]);
        atomicAdd(&pooled[g*H + col], zp);
        float v = eluf(acc3[ti][r]);
        h[(size_t)nc*H + col] = v;
        int byt = (ln << 8) + (col << 1);
        byt ^= (ln & 7) << 4;
        *(unsigned short*)((char*)hb + byt) = f2bf(v);
      }
    }
  }
  if (!has_next) return;
  __syncthreads();

  // pack GEMM from LDS h_next; 8B coalesced pack stores
  s16x8 an[4];
  #pragma unroll
  for (int ks = 0; ks < 4; ks++) {
    int byt = (row << 8) + ks*64 + kg*16;
    byt ^= (row & 7) << 4;
    an[ks] = *(s16x8*)((char*)hb + byt);
  }
  #pragma unroll
  for (int ti = 0; ti < 2; ti++) {
    int t = wave*2 + ti;
    f32x4 pacc[6];
    #pragma unroll
    for (int ch = 0; ch < 6; ch++) { pacc[ch][0]=0.f; pacc[ch][1]=0.f; pacc[ch][2]=0.f; pacc[ch][3]=0.f; }
    #pragma unroll
    for (int ch = 0; ch < 6; ch++) {
      int col = ch*128 + t*16 + row;
      #pragma unroll
      for (int ks = 0; ks < 4; ks++) {
        s16x8 b = *(const s16x8*)&wnt[(size_t)col*128 + ks*32 + kg*8];
        pacc[ch] = MFMA16(an[ks], b, pacc[ch]);
      }
    }
    int c = t*16 + row;
    #pragma unroll
    for (int r = 0; r < 4; r++) {
      int nc = nbase + kg*4 + r;
      size_t base = (size_t)nc*512 + c*4;
      unsigned int s0 = (unsigned int)f2bf(pacc[0][r]) | ((unsigned int)f2bf(pacc[2][r]) << 16);
      unsigned int s1 = (unsigned int)f2bf(pacc[3][r]) | ((unsigned int)f2bf(pacc[5][r]) << 16);
      unsigned int t0 = (unsigned int)f2bf(pacc[1][r]) | ((unsigned int)f2bf(pacc[2][r]) << 16);
      unsigned int t1 = (unsigned int)f2bf(pacc[4][r]) | ((unsigned int)f2bf(pacc[5][r]) << 16);
      *(uint2*)&spackb[base] = make_uint2(s0, s1);
      *(uint2*)&tpackb[base] = make_uint2(t0, t1);
    }
  }
}

// ---------------- final: y = elu(elu(pooled @ lr1) @ lr2) ----------------
__global__ __launch_bounds__(64) void final_kernel(
    const float* __restrict__ pooled, const float* __restrict__ lr1, const float* __restrict__ lr2,
    float* __restrict__ out)
{
  __shared__ float sp[128];
  __shared__ float y1[64];
  int g = blockIdx.x, tid = threadIdx.x;
  sp[tid]      = pooled[g*128 + tid];
  sp[tid + 64] = pooled[g*128 + 64 + tid];
  __syncthreads();
  float acc = 0.f;
  for (int k = 0; k < 128; k++) acc += sp[k] * lr1[k*64 + tid];
  y1[tid] = eluf(acc);
  __syncthreads();
  if (tid < 32) {
    float a2 = 0.f;
    for (int k = 0; k < 64; k++) a2 += y1[k] * lr2[k*32 + tid];
    out[g*32 + tid] = eluf(a2);
  }
}

extern "C" void kernel_launch(void* const* d_in, const int* in_sizes, int n_in,
                              void* d_out, int out_size, void* d_ws, size_t ws_size,
                              hipStream_t stream)
{
  const float* x    = (const float*)d_in[0];
  const float* ed   = (const float*)d_in[1];
  const float* cs   = (const float*)d_in[2];
  const float* pw   = (const float*)d_in[3];
  const float* embW = (const float*)d_in[4];
  const float* Wg   = (const float*)d_in[5];
  const float* Wm   = (const float*)d_in[6];
  const float* W1   = (const float*)d_in[7];
  const float* W2g  = (const float*)d_in[8];
  const float* W2   = (const float*)d_in[9];
  const float* p1   = (const float*)d_in[10];
  const float* p2   = (const float*)d_in[11];
  const float* psiW = (const float*)d_in[12];
  const float* lr1  = (const float*)d_in[13];
  const float* lr2  = (const float*)d_in[14];
  const int* esrc   = (const int*)d_in[15];
  const int* etgt   = (const int*)d_in[16];
  const int* gidx   = (const int*)d_in[17];

  float* h_b    = (float*)d_ws;                 // 1,280,000 f
  float* pooled = h_b + (size_t)N_NODES*H;      // 12,800 f
  unsigned short* spackb = (unsigned short*)(pooled + 100*H); // N_NODES*512 us
  unsigned short* tpackb = spackb + (size_t)N_NODES*512;      // N_NODES*512 us
  int* counts  = (int*)(tpackb + (size_t)N_NODES*512);
  int* offsets = counts + N_NODES;              // N_NODES+1 (offsets[N_NODES] = n_active)
  int* cursor  = offsets + N_NODES + 1;
  int* mcur    = cursor + N_NODES;              // 1
  int* perm    = mcur + 1;                      // N_EDGES
  int* srcp    = perm + N_EDGES;                // N_EDGES
  int* tgtp    = srcp + N_EDGES;                // N_EDGES
  float* edp   = (float*)(tgtp + N_EDGES);      // N_EDGES
  unsigned short* w1t  = (unsigned short*)(edp + N_EDGES); // 3*8192
  unsigned short* w2t  = w1t + 3*8192;
  unsigned short* w2gt = w2t + 3*8192;          // 3*4096
  unsigned short* embt = w2gt + 3*4096;         // 16384
  unsigned short* wnt  = embt + 16384;          // 3*98304
  unsigned short* wpt  = wnt + 3*98304;         // 3*49152
  unsigned short* csb  = wpt + 3*49152;         // N_EDGES*64
  unsigned short* pwb  = csb + (size_t)N_EDGES*64; // N_EDGES*64

  // one-time: edge sort by (masked, src) + de-indirect + bf16 conversions
  hipMemsetAsync(counts, 0, N_NODES*sizeof(int), stream);
  hipMemsetAsync(mcur, 0, sizeof(int), stream);
  hipMemsetAsync(pooled, 0, 100*H*sizeof(float), stream);
  hist_kernel<<<(N_EDGES+255)/256, 256, 0, stream>>>(esrc, ed, counts);
  scan_kernel<<<1, 256, 0, stream>>>(counts, offsets);
  hipMemcpyAsync(cursor, offsets, N_NODES*sizeof(int), hipMemcpyDeviceToDevice, stream);
  scatter_kernel<<<(N_EDGES+255)/256, 256, 0, stream>>>(esrc, etgt, ed, offsets,
      cursor, mcur, perm, srcp, tgtp, edp);
  prep_edges<<<N_EDGES*8/256, 256, 0, stream>>>(cs, pw, perm, offsets + N_NODES, csb, pwb);
  prep_weights<<<208, 256, 0, stream>>>(W1, W2, W2g, embW, w1t, w2t, w2gt, embt);
  prep_nodew<<<(3*98304 + 3*49152 + 255)/256, 256, 0, stream>>>(Wg, Wm, p1, p2, psiW, wnt, wpt);

  embed_pack<<<N_NODES/16, 256, 0, stream>>>(x, embt, wnt, h_b, spackb, tpackb);

  for (int i = 0; i < 3; i++) {
    fused_edge<<<N_EDGES/64, 256, 0, stream>>>(h_b, csb, pwb,
        w1t + i*8192, w2t + i*8192, w2gt + i*4096,
        srcp, tgtp, edp, offsets + N_NODES, spackb, tpackb);
    node_next<<<N_NODES/16, 256, 0, stream>>>(h_b,
        wpt + i*49152, wnt + ((i+1) % 3)*98304,
        gidx, pooled, spackb, tpackb, (i < 2) ? 1 : 0);
  }
  final_kernel<<<100, 64, 0, stream>>>(pooled, lr1, lr2, (float*)d_out);
}

// Round 16
// 382.156 us; speedup vs baseline: 1.2074x; 1.1169x over previous
//
#include <hip/hip_runtime.h>
#include <math.h>

#define H 128
#define N_NODES 10000
#define N_EDGES 160000

typedef float f32x4 __attribute__((ext_vector_type(4)));
typedef short s16x8 __attribute__((ext_vector_type(8)));

#define WAVE_LDS_FENCE() do { \
  asm volatile("s_waitcnt lgkmcnt(0)" ::: "memory"); \
  __builtin_amdgcn_sched_barrier(0); \
} while (0)

__device__ __forceinline__ float sigf(float x){ return 1.0f/(1.0f + __expf(-x)); }
__device__ __forceinline__ float eluf(float x){ return x > 0.0f ? x : (__expf(x) - 1.0f); }

__device__ __forceinline__ unsigned short f2bf(float f){
  unsigned int u = __float_as_uint(f);
  unsigned int r = (u + 0x7fffu + ((u >> 16) & 1u)) >> 16;
  return (unsigned short)r;
}
__device__ __forceinline__ float bf2f(unsigned short s){
  return __uint_as_float(((unsigned int)s) << 16);
}

__device__ __forceinline__ f32x4 MFMA16(s16x8 a, s16x8 b, f32x4 c){
  return __builtin_amdgcn_mfma_f32_16x16x32_bf16(a, b, c, 0, 0, 0);
}

__device__ __forceinline__ s16x8 loadA_f32(const float* p){
  float4 a = *(const float4*)p;
  float4 b = *(const float4*)(p+4);
  s16x8 r;
  r[0]=(short)f2bf(a.x); r[1]=(short)f2bf(a.y); r[2]=(short)f2bf(a.z); r[3]=(short)f2bf(a.w);
  r[4]=(short)f2bf(b.x); r[5]=(short)f2bf(b.y); r[6]=(short)f2bf(b.z); r[7]=(short)f2bf(b.w);
  return r;
}

// ---------------- edge sort by (masked, src) ----------------
__global__ __launch_bounds__(256) void hist_kernel(
    const int* __restrict__ src, const float* __restrict__ ed, int* __restrict__ count)
{
  int e = blockIdx.x*256 + threadIdx.x;
  if (e < N_EDGES && ed[e] < 8.0f) atomicAdd(&count[src[e]], 1);
}

// hierarchical scan: scan1 (block-local prefix) -> scan2 (block sums) -> scan3 (apply + cursor)
__global__ __launch_bounds__(256) void scan1_kernel(
    const int* __restrict__ count, int* __restrict__ lofs, int* __restrict__ bsum)
{
  __shared__ int wsum[4];
  int i = blockIdx.x*256 + threadIdx.x;
  int lane = threadIdx.x & 63, wave = threadIdx.x >> 6;
  int v = (i < N_NODES) ? count[i] : 0;
  int p = v;
  #pragma unroll
  for (int off = 1; off < 64; off <<= 1) {
    int t = __shfl_up(p, off);
    if (lane >= off) p += t;
  }
  if (lane == 63) wsum[wave] = p;
  __syncthreads();
  int wbase = 0;
  #pragma unroll
  for (int w = 0; w < 4; w++) if (w < wave) wbase += wsum[w];
  if (i < N_NODES) lofs[i] = wbase + p - v;   // exclusive prefix within block
  if (threadIdx.x == 255) bsum[blockIdx.x] = wbase + p;
}

__global__ __launch_bounds__(64) void scan2_kernel(
    int* __restrict__ bsum, int* __restrict__ nact_out, int nblocks)
{
  int lane = threadIdx.x;
  int v = (lane < nblocks) ? bsum[lane] : 0;
  int p = v;
  #pragma unroll
  for (int off = 1; off < 64; off <<= 1) {
    int t = __shfl_up(p, off);
    if (lane >= off) p += t;
  }
  if (lane < nblocks) bsum[lane] = p - v;     // exclusive block base
  if (lane == nblocks - 1) *nact_out = p;     // total actives
}

__global__ __launch_bounds__(256) void scan3_kernel(
    const int* __restrict__ lofs, const int* __restrict__ bsum,
    int* __restrict__ offsets, int* __restrict__ cursor)
{
  int i = blockIdx.x*256 + threadIdx.x;
  if (i < N_NODES) {
    int o = lofs[i] + bsum[blockIdx.x];
    offsets[i] = o;
    cursor[i]  = o;
  }
}

__global__ __launch_bounds__(256) void scatter_kernel(
    const int* __restrict__ src, const int* __restrict__ tgt, const float* __restrict__ ed,
    const int* __restrict__ offsets,
    int* __restrict__ cursor, int* __restrict__ mcur, int* __restrict__ perm,
    int* __restrict__ srcp, int* __restrict__ tgtp, float* __restrict__ edp)
{
  int e = blockIdx.x*256 + threadIdx.x;
  if (e < N_EDGES) {
    int s = src[e];
    float r = ed[e];
    int pos;
    if (r < 8.0f) pos = atomicAdd(&cursor[s], 1);
    else          pos = offsets[N_NODES] + atomicAdd(mcur, 1);
    perm[pos] = e;
    srcp[pos] = s;
    tgtp[pos] = tgt[e];
    edp[pos]  = r;
  }
}

// ---------------- prep_edges: permuted bf16 copies of cs, pw (zeros past n_active) ----------------
__global__ __launch_bounds__(256) void prep_edges(
    const float* __restrict__ cs, const float* __restrict__ pw, const int* __restrict__ perm,
    const int* __restrict__ nact,
    unsigned short* __restrict__ csb, unsigned short* __restrict__ pwb)
{
  int idx = blockIdx.x*256 + threadIdx.x;   // over N_EDGES*8
  if (idx >= N_EDGES*8) return;
  int pos = idx >> 3, kc = idx & 7;
  if (pos < *nact) {
    int e = perm[pos];
    s16x8 c = loadA_f32(&cs[(size_t)e*64 + kc*8]);
    s16x8 p = loadA_f32(&pw[(size_t)e*64 + kc*8]);
    *(s16x8*)&csb[(size_t)pos*64 + kc*8] = c;
    *(s16x8*)&pwb[(size_t)pos*64 + kc*8] = p;
  } else {
    s16x8 z = {0,0,0,0,0,0,0,0};
    *(s16x8*)&csb[(size_t)pos*64 + kc*8] = z;
    *(s16x8*)&pwb[(size_t)pos*64 + kc*8] = z;
  }
}

// ---------------- prep_weights: W1,W2 (64x128), W2g (64x64) -> bf16 [col][k] ----------------
__global__ __launch_bounds__(256) void prep_weights(
    const float* __restrict__ W1, const float* __restrict__ W2, const float* __restrict__ W2g,
    unsigned short* __restrict__ w1t, unsigned short* __restrict__ w2t,
    unsigned short* __restrict__ w2gt)
{
  int idx = blockIdx.x*256 + threadIdx.x;
  if (idx < 3*8192) {
    int l = idx / 8192, r = idx % 8192;
    int c = r >> 6, k = r & 63;
    w1t[idx] = f2bf(W1[l*8192 + k*128 + c]);
    w2t[idx] = f2bf(W2[l*8192 + k*128 + c]);
  } else if (idx < 3*8192 + 3*4096) {
    int idx2 = idx - 3*8192;
    int l = idx2 / 4096, r = idx2 % 4096;
    int c = r >> 6, k = r & 63;
    w2gt[idx2] = f2bf(W2g[l*4096 + k*64 + c]);
  }
}

// ---------------- prep_t: coalesced LDS-tile transposes of 28 128x128 f32 matrices -> bf16 ----
// m 0..8:  Wg[l][s]   -> wnt[l] rows s*128..        (l=m/3, s=m%3)
// m 9..17: Wm[l][s]   -> wnt[l] rows 384+s*128..
// m 18..26: {p1,p2,psi}[l] -> wpt[l] rows w*128..   (l=(m-18)/3, w=(m-18)%3)
// m 27: embW -> embt
__global__ __launch_bounds__(256) void prep_t(
    const float* __restrict__ Wg, const float* __restrict__ Wm,
    const float* __restrict__ p1, const float* __restrict__ p2, const float* __restrict__ psiW,
    const float* __restrict__ embW,
    unsigned short* __restrict__ wnt, unsigned short* __restrict__ wpt,
    unsigned short* __restrict__ embt)
{
  __shared__ unsigned short t[32][34];
  int m    = blockIdx.x >> 4;
  int tile = blockIdx.x & 15;
  int tr = tile >> 2, tc = tile & 3;
  const float* src; unsigned short* dst;
  if (m < 9)       { int l = m/3, s = m%3;           src = Wg  + l*49152 + s*16384; dst = wnt + l*98304 + s*16384; }
  else if (m < 18) { int mm = m-9,  l = mm/3, s = mm%3; src = Wm + l*49152 + s*16384; dst = wnt + l*98304 + 49152 + s*16384; }
  else if (m < 27) { int mm = m-18, l = mm/3, w = mm%3;
                     const float* sp = (w==0) ? p1 : (w==1) ? p2 : psiW;
                     src = sp + l*16384; dst = wpt + l*49152 + w*16384; }
  else             { src = embW; dst = embt; }

  int tx = threadIdx.x & 31, ty = threadIdx.x >> 5;   // 32 x 8
  #pragma unroll
  for (int rr = 0; rr < 4; rr++) {
    int r = ty + rr*8;
    t[r][tx] = f2bf(src[(tr*32 + r)*128 + tc*32 + tx]);
  }
  __syncthreads();
  #pragma unroll
  for (int rr = 0; rr < 4; rr++) {
    int r = ty + rr*8;
    dst[(tc*32 + r)*128 + tr*32 + tx] = t[tx][r];
  }
}

// ---------------- embed_pack: h = sig(x@embW) + layer-0 pack GEMM, 16 nodes/block ----------------
__global__ __launch_bounds__(256) void embed_pack(
    const float* __restrict__ x, const unsigned short* __restrict__ embt,
    const unsigned short* __restrict__ wnt,
    float* __restrict__ h_out,
    unsigned short* __restrict__ spackb, unsigned short* __restrict__ tpackb)
{
  __shared__ unsigned short hb[16*128];          // 4 KB swizzled bf16 h
  int tid = threadIdx.x, wave = tid >> 6, lane = tid & 63;
  int row = lane & 15, kg = lane >> 4;
  int nbase = blockIdx.x*16;
  const float* xr = &x[(size_t)(nbase + row)*H];
  s16x8 a[4];
  #pragma unroll
  for (int ks = 0; ks < 4; ks++) a[ks] = loadA_f32(xr + ks*32 + kg*8);

  f32x4 acc[2];
  #pragma unroll
  for (int ti = 0; ti < 2; ti++) { acc[ti][0]=0.f; acc[ti][1]=0.f; acc[ti][2]=0.f; acc[ti][3]=0.f; }
  #pragma unroll
  for (int ti = 0; ti < 2; ti++) {
    int col = (wave*2 + ti)*16 + row;
    #pragma unroll
    for (int ks = 0; ks < 4; ks++) {
      s16x8 b = *(const s16x8*)&embt[(size_t)col*128 + ks*32 + kg*8];
      acc[ti] = MFMA16(a[ks], b, acc[ti]);
    }
  }
  #pragma unroll
  for (int ti = 0; ti < 2; ti++) {
    int col = (wave*2 + ti)*16 + row;
    #pragma unroll
    for (int r = 0; r < 4; r++) {
      int ln = kg*4 + r;
      float v = sigf(acc[ti][r]);
      h_out[(size_t)(nbase + ln)*H + col] = v;
      int byt = (ln << 8) + (col << 1);
      byt ^= (ln & 7) << 4;
      *(unsigned short*)((char*)hb + byt) = f2bf(v);
    }
  }
  __syncthreads();

  // pack GEMM from LDS
  s16x8 an[4];
  #pragma unroll
  for (int ks = 0; ks < 4; ks++) {
    int byt = (row << 8) + ks*64 + kg*16;
    byt ^= (row & 7) << 4;
    an[ks] = *(s16x8*)((char*)hb + byt);
  }
  #pragma unroll
  for (int ti = 0; ti < 2; ti++) {
    int t = wave*2 + ti;
    f32x4 pacc[6];
    #pragma unroll
    for (int ch = 0; ch < 6; ch++) { pacc[ch][0]=0.f; pacc[ch][1]=0.f; pacc[ch][2]=0.f; pacc[ch][3]=0.f; }
    #pragma unroll
    for (int ch = 0; ch < 6; ch++) {
      int col = ch*128 + t*16 + row;
      #pragma unroll
      for (int ks = 0; ks < 4; ks++) {
        s16x8 b = *(const s16x8*)&wnt[(size_t)col*128 + ks*32 + kg*8];
        pacc[ch] = MFMA16(an[ks], b, pacc[ch]);
      }
    }
    int c = t*16 + row;
    #pragma unroll
    for (int r = 0; r < 4; r++) {
      int nc = nbase + kg*4 + r;
      size_t base = (size_t)nc*512 + c*4;
      unsigned int s0 = (unsigned int)f2bf(pacc[0][r]) | ((unsigned int)f2bf(pacc[2][r]) << 16);
      unsigned int s1 = (unsigned int)f2bf(pacc[3][r]) | ((unsigned int)f2bf(pacc[5][r]) << 16);
      unsigned int t0 = (unsigned int)f2bf(pacc[1][r]) | ((unsigned int)f2bf(pacc[2][r]) << 16);
      unsigned int t1 = (unsigned int)f2bf(pacc[4][r]) | ((unsigned int)f2bf(pacc[5][r]) << 16);
      *(uint2*)&spackb[base] = make_uint2(s0, s1);
      *(uint2*)&tpackb[base] = make_uint2(t0, t1);
    }
  }
}

// ---------------- fused edge: 16 edges/wave, wave-independent ----------------
__global__ __launch_bounds__(256) void fused_edge(
    float* __restrict__ h_acc,
    const unsigned short* __restrict__ csb, const unsigned short* __restrict__ pwb,
    const unsigned short* __restrict__ w1t, const unsigned short* __restrict__ w2t,
    const unsigned short* __restrict__ w2gt,
    const int* __restrict__ srcp, const int* __restrict__ tgtp,
    const float* __restrict__ edp, const int* __restrict__ nact,
    const unsigned short* __restrict__ spackb, const unsigned short* __restrict__ tpackb)
{
  __shared__ unsigned short zb[4][16][132];   // per-wave slice; first 2 KB doubles as gate
  __shared__ int   src_s[4][16];
  __shared__ int   tgt_s[4][16];
  __shared__ float rcp_s[4][16];

  int p0 = blockIdx.x * 64;
  if (p0 >= *nact) return;                   // fully-masked tail block

  int tid  = threadIdx.x;
  int wave = tid >> 6, lane = tid & 63;
  int row  = lane & 15, kg = lane >> 4;
  unsigned short* gate = &zb[wave][0][0];    // wave-private 2 KB overlay

  if (lane < 16) {
    int e = p0 + wave*16 + lane;
    rcp_s[wave][lane] = 1.0f / edp[e];
    src_s[wave][lane] = srcp[e];
    tgt_s[wave][lane] = tgtp[e];
  }

  int pos = p0 + wave*16 + row;
  s16x8 acs[2], apw[2];
  acs[0] = *(const s16x8*)&csb[(size_t)pos*64 + kg*8];
  acs[1] = *(const s16x8*)&csb[(size_t)pos*64 + 32 + kg*8];
  apw[0] = *(const s16x8*)&pwb[(size_t)pos*64 + kg*8];
  apw[1] = *(const s16x8*)&pwb[(size_t)pos*64 + 32 + kg*8];

  // phase A: S1 = pw @ W2g
  f32x4 acc1[4];
  #pragma unroll
  for (int nt = 0; nt < 4; nt++) { acc1[nt][0]=0.f; acc1[nt][1]=0.f; acc1[nt][2]=0.f; acc1[nt][3]=0.f; }
  #pragma unroll
  for (int nt = 0; nt < 4; nt++) {
    s16x8 b0 = *(const s16x8*)&w2gt[(size_t)(nt*16+row)*64 + kg*8];
    s16x8 b1 = *(const s16x8*)&w2gt[(size_t)(nt*16+row)*64 + 32 + kg*8];
    acc1[nt] = MFMA16(apw[0], b0, acc1[nt]);
    acc1[nt] = MFMA16(apw[1], b1, acc1[nt]);
  }

  // sigmoid -> wave-private gate (C-layout scatter, swizzled; local row = kg*4+r)
  #pragma unroll
  for (int nt = 0; nt < 4; nt++) {
    #pragma unroll
    for (int r = 0; r < 4; r++) {
      int grow = kg*4 + r;
      int gcol = nt*16 + row;
      int byt = (grow << 7) + (gcol << 1);
      byt ^= (grow & 7) << 4;
      *(unsigned short*)((char*)gate + byt) = f2bf(sigf(acc1[nt][r]));
    }
  }
  WAVE_LDS_FENCE();

  // read gate in A-layout, pwg frags = pw * gate
  s16x8 apg[2];
  #pragma unroll
  for (int ks = 0; ks < 2; ks++) {
    int byt = (row << 7) + ks*64 + kg*16;
    byt ^= (row & 7) << 4;
    s16x8 g = *(s16x8*)((char*)gate + byt);
    s16x8 o;
    #pragma unroll
    for (int j = 0; j < 8; j++) {
      float v = bf2f((unsigned short)apw[ks][j]) * bf2f((unsigned short)g[j]);
      o[j] = (short)f2bf(v);
    }
    apg[ks] = o;
  }
  WAVE_LDS_FENCE();

  // phase B: az = cs@W1t + pwg@W2t
  f32x4 acc2[8];
  #pragma unroll
  for (int nt = 0; nt < 8; nt++) { acc2[nt][0]=0.f; acc2[nt][1]=0.f; acc2[nt][2]=0.f; acc2[nt][3]=0.f; }
  #pragma unroll
  for (int nt = 0; nt < 8; nt++) {
    #pragma unroll
    for (int ks = 0; ks < 2; ks++) {
      s16x8 b1 = *(const s16x8*)&w1t[(size_t)(nt*16+row)*64 + ks*32 + kg*8];
      acc2[nt] = MFMA16(acs[ks], b1, acc2[nt]);
      s16x8 b2 = *(const s16x8*)&w2t[(size_t)(nt*16+row)*64 + ks*32 + kg*8];
      acc2[nt] = MFMA16(apg[ks], b2, acc2[nt]);
    }
  }

  // phase C: az -> wave-private zb
  #pragma unroll
  for (int nt = 0; nt < 8; nt++) {
    #pragma unroll
    for (int r = 0; r < 4; r++) {
      zb[wave][kg*4 + r][nt*16 + row] = f2bf(acc2[nt][r]);
    }
  }
  WAVE_LDS_FENCE();

  // phase D: wave's 16 edges, batches of 4
  {
    int l = lane;
    int cur = src_s[wave][0];
    s16x8 sp = *(const s16x8*)&spackb[(size_t)cur*512 + l*8];
    float Ags0 = bf2f((unsigned short)sp[0]), Cgs0 = bf2f((unsigned short)sp[1]);
    float Ams0 = bf2f((unsigned short)sp[2]), Cms0 = bf2f((unsigned short)sp[3]);
    float Ags1 = bf2f((unsigned short)sp[4]), Cgs1 = bf2f((unsigned short)sp[5]);
    float Ams1 = bf2f((unsigned short)sp[6]), Cms1 = bf2f((unsigned short)sp[7]);
    float acc0 = 0.f, accB = 0.f;
    for (int eb = 0; eb < 16; eb += 4) {
      s16x8 tp[4]; unsigned int zz[4];
      #pragma unroll
      for (int b = 0; b < 4; b++) {
        int e = eb + b;
        tp[b] = *(const s16x8*)&tpackb[(size_t)tgt_s[wave][e]*512 + l*8];
        zz[b] = *(const unsigned int*)&zb[wave][e][2*l];
      }
      #pragma unroll
      for (int b = 0; b < 4; b++) {
        int e = eb + b;
        int sn = src_s[wave][e];
        if (sn != cur) {   // wave-uniform (src-sorted)
          atomicAdd(&h_acc[(size_t)cur*H + 2*l],     acc0);
          atomicAdd(&h_acc[(size_t)cur*H + 2*l + 1], accB);
          acc0 = 0.f; accB = 0.f; cur = sn;
          sp = *(const s16x8*)&spackb[(size_t)cur*512 + l*8];
          Ags0 = bf2f((unsigned short)sp[0]); Cgs0 = bf2f((unsigned short)sp[1]);
          Ams0 = bf2f((unsigned short)sp[2]); Cms0 = bf2f((unsigned short)sp[3]);
          Ags1 = bf2f((unsigned short)sp[4]); Cgs1 = bf2f((unsigned short)sp[5]);
          Ams1 = bf2f((unsigned short)sp[6]); Cms1 = bf2f((unsigned short)sp[7]);
        }
        float rc = rcp_s[wave][e];
        float z0 = bf2f((unsigned short)(zz[b] & 0xffffu));
        float z1 = bf2f((unsigned short)(zz[b] >> 16));
        float Bg0 = bf2f((unsigned short)tp[b][0]), Cg0 = bf2f((unsigned short)tp[b][1]);
        float Bm0 = bf2f((unsigned short)tp[b][2]), Cm0 = bf2f((unsigned short)tp[b][3]);
        float Bg1 = bf2f((unsigned short)tp[b][4]), Cg1 = bf2f((unsigned short)tp[b][5]);
        float Bm1 = bf2f((unsigned short)tp[b][6]), Cm1 = bf2f((unsigned short)tp[b][7]);
        float g0 = sigf(Ags0 + Bg0 + rc*(Cgs0 - Cg0));
        float m0 = eluf(Ams0 + Bm0 + rc*(Cms0 - Cm0));
        acc0 += g0 * m0 * z0;
        float g1 = sigf(Ags1 + Bg1 + rc*(Cgs1 - Cg1));
        float m1 = eluf(Ams1 + Bm1 + rc*(Cms1 - Cm1));
        accB += g1 * m1 * z1;
      }
    }
    atomicAdd(&h_acc[(size_t)cur*H + 2*l],     acc0);
    atomicAdd(&h_acc[(size_t)cur*H + 2*l + 1], accB);
  }
}

// ---------------- node_next: 16 nodes/block, 4 waves + race-fix barrier ----------------
__global__ __launch_bounds__(256) void node_next(
    float* __restrict__ h,                       // in/out (in-place update)
    const unsigned short* __restrict__ wpt,      // this layer p1/p2/psi
    const unsigned short* __restrict__ wnt,      // NEXT layer Wg/Wm
    const int* __restrict__ gidx, float* __restrict__ pooled,
    unsigned short* __restrict__ spackb, unsigned short* __restrict__ tpackb,
    int has_next)
{
  __shared__ unsigned short hb[16*128];          // 4 KB swizzled bf16 h_next
  int tid = threadIdx.x, wave = tid >> 6, lane = tid & 63;
  int row = lane & 15, kg = lane >> 4;
  int nbase = blockIdx.x*16;
  const float* hr = &h[(size_t)(nbase + row)*H];
  s16x8 a[4];
  #pragma unroll
  for (int ks = 0; ks < 4; ks++) a[ks] = loadA_f32(hr + ks*32 + kg*8);
  __syncthreads();   // RACE FIX: all waves' h reads complete before any wave writes h in-place

  f32x4 acc1[2], acc2[2], acc3[2];
  #pragma unroll
  for (int ti = 0; ti < 2; ti++) {
    #pragma unroll
    for (int r = 0; r < 4; r++) { acc1[ti][r]=0.f; acc2[ti][r]=0.f; acc3[ti][r]=0.f; }
  }
  #pragma unroll
  for (int ti = 0; ti < 2; ti++) {
    int col = (wave*2 + ti)*16 + row;
    #pragma unroll
    for (int ks = 0; ks < 4; ks++) {
      s16x8 b1 = *(const s16x8*)&wpt[(size_t)(col      )*128 + ks*32 + kg*8];
      s16x8 b2 = *(const s16x8*)&wpt[(size_t)(col + 128)*128 + ks*32 + kg*8];
      s16x8 b3 = *(const s16x8*)&wpt[(size_t)(col + 256)*128 + ks*32 + kg*8];
      acc1[ti] = MFMA16(a[ks], b1, acc1[ti]);
      acc2[ti] = MFMA16(a[ks], b2, acc2[ti]);
      acc3[ti] = MFMA16(a[ks], b3, acc3[ti]);
    }
  }

  int nc0 = nbase + kg*4;
  int g0 = gidx[nc0], g3 = gidx[nc0 + 3];
  if (g0 == g3) {
    #pragma unroll
    for (int ti = 0; ti < 2; ti++) {
      int col = (wave*2 + ti)*16 + row;
      float s = 0.f;
      #pragma unroll
      for (int r = 0; r < 4; r++) s += eluf(acc1[ti][r] * acc2[ti][r]);
      atomicAdd(&pooled[g0*H + col], s);
      #pragma unroll
      for (int r = 0; r < 4; r++) {
        int ln = kg*4 + r;
        float v = eluf(acc3[ti][r]);
        h[(size_t)(nc0 + r)*H + col] = v;
        int byt = (ln << 8) + (col << 1);
        byt ^= (ln & 7) << 4;
        *(unsigned short*)((char*)hb + byt) = f2bf(v);
      }
    }
  } else {
    #pragma unroll
    for (int r = 0; r < 4; r++) {
      int nc = nc0 + r;
      int ln = kg*4 + r;
      int g = gidx[nc];
      #pragma unroll
      for (int ti = 0; ti < 2; ti++) {
        int col = (wave*2 + ti)*16 + row;
        float zp = eluf(acc1[ti][r] * acc2[ti][r]);
        atomicAdd(&pooled[g*H + col], zp);
        float v = eluf(acc3[ti][r]);
        h[(size_t)nc*H + col] = v;
        int byt = (ln << 8) + (col << 1);
        byt ^= (ln & 7) << 4;
        *(unsigned short*)((char*)hb + byt) = f2bf(v);
      }
    }
  }
  if (!has_next) return;
  __syncthreads();

  // pack GEMM from LDS h_next; 8B coalesced pack stores
  s16x8 an[4];
  #pragma unroll
  for (int ks = 0; ks < 4; ks++) {
    int byt = (row << 8) + ks*64 + kg*16;
    byt ^= (row & 7) << 4;
    an[ks] = *(s16x8*)((char*)hb + byt);
  }
  #pragma unroll
  for (int ti = 0; ti < 2; ti++) {
    int t = wave*2 + ti;
    f32x4 pacc[6];
    #pragma unroll
    for (int ch = 0; ch < 6; ch++) { pacc[ch][0]=0.f; pacc[ch][1]=0.f; pacc[ch][2]=0.f; pacc[ch][3]=0.f; }
    #pragma unroll
    for (int ch = 0; ch < 6; ch++) {
      int col = ch*128 + t*16 + row;
      #pragma unroll
      for (int ks = 0; ks < 4; ks++) {
        s16x8 b = *(const s16x8*)&wnt[(size_t)col*128 + ks*32 + kg*8];
        pacc[ch] = MFMA16(an[ks], b, pacc[ch]);
      }
    }
    int c = t*16 + row;
    #pragma unroll
    for (int r = 0; r < 4; r++) {
      int nc = nbase + kg*4 + r;
      size_t base = (size_t)nc*512 + c*4;
      unsigned int s0 = (unsigned int)f2bf(pacc[0][r]) | ((unsigned int)f2bf(pacc[2][r]) << 16);
      unsigned int s1 = (unsigned int)f2bf(pacc[3][r]) | ((unsigned int)f2bf(pacc[5][r]) << 16);
      unsigned int t0 = (unsigned int)f2bf(pacc[1][r]) | ((unsigned int)f2bf(pacc[2][r]) << 16);
      unsigned int t1 = (unsigned int)f2bf(pacc[4][r]) | ((unsigned int)f2bf(pacc[5][r]) << 16);
      *(uint2*)&spackb[base] = make_uint2(s0, s1);
      *(uint2*)&tpackb[base] = make_uint2(t0, t1);
    }
  }
}

// ---------------- final: y = elu(elu(pooled @ lr1) @ lr2) ----------------
__global__ __launch_bounds__(64) void final_kernel(
    const float* __restrict__ pooled, const float* __restrict__ lr1, const float* __restrict__ lr2,
    float* __restrict__ out)
{
  __shared__ float sp[128];
  __shared__ float y1[64];
  int g = blockIdx.x, tid = threadIdx.x;
  sp[tid]      = pooled[g*128 + tid];
  sp[tid + 64] = pooled[g*128 + 64 + tid];
  __syncthreads();
  float acc = 0.f;
  for (int k = 0; k < 128; k++) acc += sp[k] * lr1[k*64 + tid];
  y1[tid] = eluf(acc);
  __syncthreads();
  if (tid < 32) {
    float a2 = 0.f;
    for (int k = 0; k < 64; k++) a2 += y1[k] * lr2[k*32 + tid];
    out[g*32 + tid] = eluf(a2);
  }
}

extern "C" void kernel_launch(void* const* d_in, const int* in_sizes, int n_in,
                              void* d_out, int out_size, void* d_ws, size_t ws_size,
                              hipStream_t stream)
{
  const float* x    = (const float*)d_in[0];
  const float* ed   = (const float*)d_in[1];
  const float* cs   = (const float*)d_in[2];
  const float* pw   = (const float*)d_in[3];
  const float* embW = (const float*)d_in[4];
  const float* Wg   = (const float*)d_in[5];
  const float* Wm   = (const float*)d_in[6];
  const float* W1   = (const float*)d_in[7];
  const float* W2g  = (const float*)d_in[8];
  const float* W2   = (const float*)d_in[9];
  const float* p1   = (const float*)d_in[10];
  const float* p2   = (const float*)d_in[11];
  const float* psiW = (const float*)d_in[12];
  const float* lr1  = (const float*)d_in[13];
  const float* lr2  = (const float*)d_in[14];
  const int* esrc   = (const int*)d_in[15];
  const int* etgt   = (const int*)d_in[16];
  const int* gidx   = (const int*)d_in[17];

  float* h_b    = (float*)d_ws;                 // 1,280,000 f
  float* pooled = h_b + (size_t)N_NODES*H;      // 12,800 f
  unsigned short* spackb = (unsigned short*)(pooled + 100*H); // N_NODES*512 us
  unsigned short* tpackb = spackb + (size_t)N_NODES*512;      // N_NODES*512 us
  int* counts  = (int*)(tpackb + (size_t)N_NODES*512);
  int* offsets = counts + N_NODES;              // N_NODES+1 (offsets[N_NODES] = n_active)
  int* cursor  = offsets + N_NODES + 1;
  int* mcur    = cursor + N_NODES;              // 1
  int* perm    = mcur + 1;                      // N_EDGES
  int* srcp    = perm + N_EDGES;                // N_EDGES
  int* tgtp    = srcp + N_EDGES;                // N_EDGES
  float* edp   = (float*)(tgtp + N_EDGES);      // N_EDGES
  unsigned short* w1t  = (unsigned short*)(edp + N_EDGES); // 3*8192
  unsigned short* w2t  = w1t + 3*8192;
  unsigned short* w2gt = w2t + 3*8192;          // 3*4096
  unsigned short* embt = w2gt + 3*4096;         // 16384
  unsigned short* wnt  = embt + 16384;          // 3*98304
  unsigned short* wpt  = wnt + 3*98304;         // 3*49152
  unsigned short* csb  = wpt + 3*49152;         // N_EDGES*64
  unsigned short* pwb  = csb + (size_t)N_EDGES*64; // N_EDGES*64
  int* lofs    = (int*)(pwb + (size_t)N_EDGES*64); // N_NODES
  int* bsum    = lofs + N_NODES;                // 64

  const int SCAN_BLOCKS = (N_NODES + 255)/256;  // 40

  // one-time: edge sort by (masked, src) + de-indirect + bf16 conversions
  hipMemsetAsync(counts, 0, N_NODES*sizeof(int), stream);
  hipMemsetAsync(mcur, 0, sizeof(int), stream);
  hipMemsetAsync(pooled, 0, 100*H*sizeof(float), stream);
  hist_kernel<<<(N_EDGES+255)/256, 256, 0, stream>>>(esrc, ed, counts);
  scan1_kernel<<<SCAN_BLOCKS, 256, 0, stream>>>(counts, lofs, bsum);
  scan2_kernel<<<1, 64, 0, stream>>>(bsum, offsets + N_NODES, SCAN_BLOCKS);
  scan3_kernel<<<SCAN_BLOCKS, 256, 0, stream>>>(lofs, bsum, offsets, cursor);
  scatter_kernel<<<(N_EDGES+255)/256, 256, 0, stream>>>(esrc, etgt, ed, offsets,
      cursor, mcur, perm, srcp, tgtp, edp);
  prep_edges<<<N_EDGES*8/256, 256, 0, stream>>>(cs, pw, perm, offsets + N_NODES, csb, pwb);
  prep_weights<<<(3*8192 + 3*4096 + 255)/256, 256, 0, stream>>>(W1, W2, W2g, w1t, w2t, w2gt);
  prep_t<<<28*16, 256, 0, stream>>>(Wg, Wm, p1, p2, psiW, embW, wnt, wpt, embt);

  embed_pack<<<N_NODES/16, 256, 0, stream>>>(x, embt, wnt, h_b, spackb, tpackb);

  for (int i = 0; i < 3; i++) {
    fused_edge<<<N_EDGES/64, 256, 0, stream>>>(h_b, csb, pwb,
        w1t + i*8192, w2t + i*8192, w2gt + i*4096,
        srcp, tgtp, edp, offsets + N_NODES, spackb, tpackb);
    node_next<<<N_NODES/16, 256, 0, stream>>>(h_b,
        wpt + i*49152, wnt + ((i+1) % 3)*98304,
        gidx, pooled, spackb, tpackb, (i < 2) ? 1 : 0);
  }
  final_kernel<<<100, 64, 0, stream>>>(pooled, lr1, lr2, (float*)d_out);
}